// Round 1
// baseline (394.460 us; speedup 1.0000x reference)
//
#include <hip/hip_runtime.h>

#define NUM_HEADS 16
#define HEAD_DIM 64
#define EMBED 1024

typedef __attribute__((ext_vector_type(8))) short short8;
typedef __attribute__((ext_vector_type(4))) float f32x4;

__device__ __forceinline__ short f2bf(float f) {
  unsigned u = __builtin_bit_cast(unsigned, f);
  u += 0x7fffu + ((u >> 16) & 1u);
  return (short)(u >> 16);
}

__device__ __forceinline__ void gload_lds16(const void* g, void* l) {
  __builtin_amdgcn_global_load_lds(
      (const __attribute__((address_space(1))) void*)g,
      (__attribute__((address_space(3))) void*)l,
      16, 0, 0);
}

// -------- elementwise fp32 -> bf16 cast (8 elems/thread) --------
__global__ void cast_bf16(const float* __restrict__ in, short* __restrict__ out, int n) {
  int i = (blockIdx.x * 256 + threadIdx.x) * 8;
  if (i >= n) return;
  float4 f0 = *(const float4*)(in + i);
  float4 f1 = *(const float4*)(in + i + 4);
  short8 r;
  r[0] = f2bf(f0.x); r[1] = f2bf(f0.y); r[2] = f2bf(f0.z); r[3] = f2bf(f0.w);
  r[4] = f2bf(f1.x); r[5] = f2bf(f1.y); r[6] = f2bf(f1.z); r[7] = f2bf(f1.w);
  *(short8*)(out + i) = r;
}

// -------- tiled transpose + cast: in (R x C) f32 -> out (C x R) bf16 --------
__global__ void transpose_cast(const float* __restrict__ in, short* __restrict__ out,
                               int R, int C) {
  __shared__ float t[32][33];
  int bx = blockIdx.x * 32;  // col base in input
  int by = blockIdx.y * 32;  // row base in input
  int tx = threadIdx.x & 31, ty = threadIdx.x >> 5;  // 32 x 8
#pragma unroll
  for (int i = 0; i < 32; i += 8)
    t[ty + i][tx] = in[(size_t)(by + ty + i) * C + bx + tx];
  __syncthreads();
#pragma unroll
  for (int i = 0; i < 32; i += 8)
    out[(size_t)(bx + ty + i) * R + by + tx] = f2bf(t[tx][ty + i]);
}

// -------- bf16 GEMM, C = A (MxK) * Bt^T (Bt is NxK) ; epilogue (acc+bias)*scale ----
template <bool OUT_F32>
__global__ __launch_bounds__(256)
void gemm_bt(const short* __restrict__ A, const short* __restrict__ Bt,
             const float* __restrict__ bias, void* __restrict__ Cptr,
             int M, int N, int K, float scale) {
  __shared__ short As[128 * 32];
  __shared__ short Bs[128 * 32];
  const int tid = threadIdx.x;
  const int wave = tid >> 6, lane = tid & 63;
  const int quad = lane >> 4, l16 = lane & 15;
  const int wr = wave >> 1, wc = wave & 1;
  const int m0 = blockIdx.x * 128, n0 = blockIdx.y * 128;

  f32x4 acc[4][4];
#pragma unroll
  for (int i = 0; i < 4; i++)
#pragma unroll
    for (int j = 0; j < 4; j++) acc[i][j] = (f32x4)0.f;

  const int c0 = wave * 2, c1 = wave * 2 + 1;
  const int rowA0 = c0 * 16 + (lane >> 2);
  const int rowA1 = c1 * 16 + (lane >> 2);
  const int kecol = (lane & 3) * 8;

  for (int k0 = 0; k0 < K; k0 += 32) {
    __syncthreads();
    gload_lds16(A + (size_t)(m0 + rowA0) * K + k0 + kecol, (char*)As + c0 * 1024);
    gload_lds16(A + (size_t)(m0 + rowA1) * K + k0 + kecol, (char*)As + c1 * 1024);
    gload_lds16(Bt + (size_t)(n0 + rowA0) * K + k0 + kecol, (char*)Bs + c0 * 1024);
    gload_lds16(Bt + (size_t)(n0 + rowA1) * K + k0 + kecol, (char*)Bs + c1 * 1024);
    __syncthreads();
    short8 a[4], b[4];
#pragma unroll
    for (int i = 0; i < 4; i++)
      a[i] = *(const short8*)(As + (wr * 64 + i * 16 + l16) * 32 + quad * 8);
#pragma unroll
    for (int j = 0; j < 4; j++)
      b[j] = *(const short8*)(Bs + (wc * 64 + j * 16 + l16) * 32 + quad * 8);
#pragma unroll
    for (int i = 0; i < 4; i++)
#pragma unroll
      for (int j = 0; j < 4; j++)
        acc[i][j] = __builtin_amdgcn_mfma_f32_16x16x32_bf16(a[i], b[j], acc[i][j], 0, 0, 0);
  }

#pragma unroll
  for (int j = 0; j < 4; j++) {
    int col = n0 + wc * 64 + j * 16 + l16;
    float bv = bias ? bias[col] : 0.f;
#pragma unroll
    for (int i = 0; i < 4; i++) {
      int rbase = m0 + wr * 64 + i * 16 + quad * 4;
#pragma unroll
      for (int r = 0; r < 4; r++) {
        float v = (acc[i][j][r] + bv) * scale;
        if (OUT_F32)
          ((float*)Cptr)[(size_t)(rbase + r) * N + col] = v;
        else
          ((short*)Cptr)[(size_t)(rbase + r) * N + col] = f2bf(v);
      }
    }
  }
}

// -------- fused flash attention: qp (B*Nq x 1024, pre-scaled), kvp (B*Nkv x 2048) ----
__global__ __launch_bounds__(256)
void attn(const short* __restrict__ qp, const short* __restrict__ kvp,
          short* __restrict__ aout, int B, int Nq, int Nkv) {
  __shared__ short Qs[64 * 64];
  __shared__ short Ks[64 * 64];
  __shared__ short Vts[64 * 64];  // Vts[d][kv]
  __shared__ short Ps[64 * 64];

  const int tid = threadIdx.x;
  const int wave = tid >> 6, lane = tid & 63;
  const int quad = lane >> 4, l16 = lane & 15;
  const int bh = blockIdx.y;
  const int b = bh >> 4, h = bh & 15;
  const int q0 = blockIdx.x * 64;

  {  // Q tile: 64 rows x 64 cols
    int r = tid >> 2, cc = (tid & 3) * 16;
    const short* src = qp + ((size_t)b * Nq + q0 + r) * EMBED + h * HEAD_DIM + cc;
    *(uint4*)(Qs + r * 64 + cc) = *(const uint4*)src;
    *(uint4*)(Qs + r * 64 + cc + 8) = *(const uint4*)(src + 8);
  }

  float m_i[4] = {-1e30f, -1e30f, -1e30f, -1e30f};
  float l_i[4] = {0.f, 0.f, 0.f, 0.f};
  f32x4 acc[4];
#pragma unroll
  for (int nt = 0; nt < 4; nt++) acc[nt] = (f32x4)0.f;

  for (int kv0 = 0; kv0 < Nkv; kv0 += 64) {
    __syncthreads();
    {  // K tile
      int r = tid >> 2, cc = (tid & 3) * 16;
      const short* sk = kvp + ((size_t)b * Nkv + kv0 + r) * 2048 + h * HEAD_DIM + cc;
      *(uint4*)(Ks + r * 64 + cc) = *(const uint4*)sk;
      *(uint4*)(Ks + r * 64 + cc + 8) = *(const uint4*)(sk + 8);
    }
    {  // V tile, transposed into Vts[d][kv]
#pragma unroll
      for (int half = 0; half < 2; ++half) {
        int r = (tid >> 3) + half * 32;
        int c0v = (tid & 7) * 8;
        const short* sv =
            kvp + ((size_t)b * Nkv + kv0 + r) * 2048 + 1024 + h * HEAD_DIM + c0v;
        uint4 d = *(const uint4*)sv;
        const short* pd = (const short*)&d;
#pragma unroll
        for (int jj = 0; jj < 8; ++jj) Vts[(c0v + jj) * 64 + r] = pd[jj];
      }
    }
    __syncthreads();

    // S strip = Q(16 rows of this wave) x K^T (64 kv)
    f32x4 s[4];
#pragma unroll
    for (int jt = 0; jt < 4; jt++) s[jt] = (f32x4)0.f;
    short8 aq0 = *(const short8*)(Qs + (wave * 16 + l16) * 64 + quad * 8);
    short8 aq1 = *(const short8*)(Qs + (wave * 16 + l16) * 64 + 32 + quad * 8);
#pragma unroll
    for (int jt = 0; jt < 4; ++jt) {
      short8 b0 = *(const short8*)(Ks + (jt * 16 + l16) * 64 + quad * 8);
      short8 b1 = *(const short8*)(Ks + (jt * 16 + l16) * 64 + 32 + quad * 8);
      s[jt] = __builtin_amdgcn_mfma_f32_16x16x32_bf16(aq0, b0, s[jt], 0, 0, 0);
      s[jt] = __builtin_amdgcn_mfma_f32_16x16x32_bf16(aq1, b1, s[jt], 0, 0, 0);
    }

    // online softmax; lane owns rows quad*4+j of this wave's strip
#pragma unroll
    for (int j = 0; j < 4; ++j) {
      float mx = fmaxf(fmaxf(s[0][j], s[1][j]), fmaxf(s[2][j], s[3][j]));
#pragma unroll
      for (int off = 1; off < 16; off <<= 1) mx = fmaxf(mx, __shfl_xor(mx, off));
      float mn = fmaxf(m_i[j], mx);
      float al = __expf(m_i[j] - mn);
      float rs = 0.f;
#pragma unroll
      for (int jt = 0; jt < 4; ++jt) {
        float p = __expf(s[jt][j] - mn);
        s[jt][j] = p;
        rs += p;
      }
#pragma unroll
      for (int off = 1; off < 16; off <<= 1) rs += __shfl_xor(rs, off);
      l_i[j] = l_i[j] * al + rs;
      m_i[j] = mn;
#pragma unroll
      for (int nt = 0; nt < 4; ++nt) acc[nt][j] *= al;
      int prow = (wave * 16 + quad * 4 + j) * 64;
#pragma unroll
      for (int jt = 0; jt < 4; ++jt) Ps[prow + jt * 16 + l16] = f2bf(s[jt][j]);
    }

    // O += P * V   (A = P strip from LDS, B = V via Vts)
    short8 ap0 = *(const short8*)(Ps + (wave * 16 + l16) * 64 + quad * 8);
    short8 ap1 = *(const short8*)(Ps + (wave * 16 + l16) * 64 + 32 + quad * 8);
#pragma unroll
    for (int nt = 0; nt < 4; ++nt) {
      short8 b0 = *(const short8*)(Vts + (nt * 16 + l16) * 64 + quad * 8);
      short8 b1 = *(const short8*)(Vts + (nt * 16 + l16) * 64 + 32 + quad * 8);
      acc[nt] = __builtin_amdgcn_mfma_f32_16x16x32_bf16(ap0, b0, acc[nt], 0, 0, 0);
      acc[nt] = __builtin_amdgcn_mfma_f32_16x16x32_bf16(ap1, b1, acc[nt], 0, 0, 0);
    }
  }

#pragma unroll
  for (int j = 0; j < 4; ++j) {
    float inv = 1.f / l_i[j];
    size_t row = (size_t)b * Nq + q0 + wave * 16 + quad * 4 + j;
#pragma unroll
    for (int nt = 0; nt < 4; ++nt)
      aout[row * EMBED + h * HEAD_DIM + nt * 16 + l16] = f2bf(acc[nt][j] * inv);
  }
}

extern "C" void kernel_launch(void* const* d_in, const int* in_sizes, int n_in,
                              void* d_out, int out_size, void* d_ws, size_t ws_size,
                              hipStream_t stream) {
  const float* q = (const float*)d_in[0];
  const float* kv = (const float*)d_in[1];
  const float* w_q = (const float*)d_in[2];
  const float* b_q = (const float*)d_in[3];
  const float* w_kv = (const float*)d_in[4];
  const float* b_kv = (const float*)d_in[5];
  const float* w_out = (const float*)d_in[6];
  const float* b_out = (const float*)d_in[7];

  const int B = 2, Nq = 2048, Nkv = 2048, C = 1024;
  const int Mq = B * Nq;  // 4096

  char* ws = (char*)d_ws;
  short* q_bf = (short*)ws;                      // Mq*C
  short* kv_bf = q_bf + (size_t)Mq * C;          // Mq*C
  short* wqt = kv_bf + (size_t)Mq * C;           // C*C
  short* wkvt = wqt + (size_t)C * C;             // 2C*C
  short* wot = wkvt + (size_t)2 * C * C;         // C*C
  short* qp = wot + (size_t)C * C;               // Mq*C
  short* kvp = qp + (size_t)Mq * C;              // Mq*2C
  short* aout = kvp + (size_t)Mq * 2 * C;        // Mq*C

  cast_bf16<<<Mq * C / 8 / 256, 256, 0, stream>>>(q, q_bf, Mq * C);
  cast_bf16<<<Mq * C / 8 / 256, 256, 0, stream>>>(kv, kv_bf, Mq * C);
  transpose_cast<<<dim3(C / 32, C / 32), 256, 0, stream>>>(w_q, wqt, C, C);
  transpose_cast<<<dim3(2 * C / 32, C / 32), 256, 0, stream>>>(w_kv, wkvt, C, 2 * C);
  transpose_cast<<<dim3(C / 32, C / 32), 256, 0, stream>>>(w_out, wot, C, C);

  const float scale = 0.125f;  // HEAD_DIM^-0.5
  gemm_bt<false><<<dim3(Mq / 128, C / 128), 256, 0, stream>>>(
      q_bf, wqt, b_q, qp, Mq, C, C, scale);
  gemm_bt<false><<<dim3(Mq / 128, 2 * C / 128), 256, 0, stream>>>(
      kv_bf, wkvt, b_kv, kvp, Mq, 2 * C, C, 1.f);
  attn<<<dim3(Nq / 64, B * NUM_HEADS), 256, 0, stream>>>(qp, kvp, aout, B, Nq, Nkv);
  gemm_bt<true><<<dim3(Mq / 128, C / 128), 256, 0, stream>>>(
      aout, wot, b_out, d_out, Mq, C, C, 1.f);
}